// Round 4
// baseline (166.017 us; speedup 1.0000x reference)
//
#include <hip/hip_runtime.h>
#include <hip/hip_bf16.h>
#include <math.h>

// Problem constants (match reference)
#define BB 2
#define LL 4096
#define DD 128
#define ED 256
#define NN 16
#define KK 4
#define RR 8
#define HH 256
#define NT (BB*LL)          // 8192 tokens
#define NC 128              // chunks for scan
#define LC 32               // chunk length (NC*LC == LL)

#define LOG2E 1.4426950408889634f

typedef __attribute__((ext_vector_type(8))) short short8;
typedef __attribute__((ext_vector_type(8))) unsigned short ushort8v;
typedef __attribute__((ext_vector_type(4))) float floatx4;

__device__ __forceinline__ unsigned short f2bf(float f) {
  unsigned int b = __builtin_bit_cast(unsigned int, f);
  b += 0x7FFFu + ((b >> 16) & 1u);           // round-to-nearest-even
  return (unsigned short)(b >> 16);
}

__device__ __forceinline__ float exp2_fast(float x) {
#if __has_builtin(__builtin_amdgcn_exp2f)
  return __builtin_amdgcn_exp2f(x);
#else
  return exp2f(x);
#endif
}

__device__ __forceinline__ ushort8v pack8(const float4& v0, const float4& v1) {
  ushort8v p;
  p[0]=f2bf(v0.x); p[1]=f2bf(v0.y); p[2]=f2bf(v0.z); p[3]=f2bf(v0.w);
  p[4]=f2bf(v1.x); p[5]=f2bf(v1.y); p[6]=f2bf(v1.z); p[7]=f2bf(v1.w);
  return p;
}

// ---------------------------------------------------------------------------
// scan1g: per-chunk fused pipeline (unchanged from round 3).
// ---------------------------------------------------------------------------
__global__ __launch_bounds__(256) void scan1g_k(
    const float* __restrict__ x,
    const float* __restrict__ g1, const float* __restrict__ b1,
    const float* __restrict__ g2, const float* __restrict__ b2,
    const float* __restrict__ in_w,
    const float* __restrict__ cw, const float* __restrict__ cb,
    const float* __restrict__ xpw,
    const float* __restrict__ dtw, const float* __restrict__ dtb,
    const float* __restrict__ A_log,
    float* __restrict__ uc, float* __restrict__ dbc,
    float* __restrict__ delta, float* __restrict__ gate,
    float* __restrict__ cA, float* __restrict__ cH) {
  __shared__ __align__(16) unsigned char SM[69776];
  auto Atile = reinterpret_cast<unsigned short(*)[136]>(SM);
  auto Wch   = reinterpret_cast<unsigned short(*)[136]>(SM);
  auto As    = reinterpret_cast<unsigned short(*)[264]>(SM);
  auto sdel  = reinterpret_cast<float(*)[128]>(SM);
  auto ubuf  = reinterpret_cast<float(*)[257]>(SM + 17408);
  auto Bs    = reinterpret_cast<unsigned short(*)[264]>(SM + 17408);
  auto sdbc  = reinterpret_cast<float(*)[40]>(SM + 17408);
  auto sus   = reinterpret_cast<float(*)[128]>(SM + 53392);

  const int eb = blockIdx.x, c = blockIdx.y, b = blockIdx.z;
  const int tid = threadIdx.x;
  const int t0 = b*LL + c*LC;
  const int wave = tid >> 6, lane = tid & 63;
  const int quad = lane >> 4, l16 = lane & 15;

  // --- P1: double-LN of x rows (t0-3 .. t0+31) -> Atile bf16 [48][136] ---
  {
    const int lr = tid >> 2, lk = (tid & 3) * 32;
    if (lr < 48) {
      if (lr < 35 && !(c == 0 && lr < 3)) {
        const float* Ap = x + (size_t)(t0 - 3 + lr)*DD + lk;
        float4 av[8];
        float s = 0.f, sq = 0.f;
        #pragma unroll
        for (int g = 0; g < 8; g++) {
          av[g] = *(const float4*)(Ap + g*4);
          s  += av[g].x + av[g].y + av[g].z + av[g].w;
          sq += av[g].x*av[g].x + av[g].y*av[g].y + av[g].z*av[g].z + av[g].w*av[g].w;
        }
        s += __shfl_xor(s, 1);  s += __shfl_xor(s, 2);
        sq += __shfl_xor(sq, 1); sq += __shfl_xor(sq, 2);
        const float m1 = s * (1.f/128.f);
        const float rs1 = rsqrtf(sq*(1.f/128.f) - m1*m1 + 1e-5f);
        float s2 = 0.f, sq2 = 0.f;
        #pragma unroll
        for (int g = 0; g < 8; g++) {
          const float4 gg = *(const float4*)(g1 + lk + g*4);
          const float4 bb = *(const float4*)(b1 + lk + g*4);
          av[g].x = (av[g].x - m1)*rs1*gg.x + bb.x;
          av[g].y = (av[g].y - m1)*rs1*gg.y + bb.y;
          av[g].z = (av[g].z - m1)*rs1*gg.z + bb.z;
          av[g].w = (av[g].w - m1)*rs1*gg.w + bb.w;
          s2  += av[g].x + av[g].y + av[g].z + av[g].w;
          sq2 += av[g].x*av[g].x + av[g].y*av[g].y + av[g].z*av[g].z + av[g].w*av[g].w;
        }
        s2 += __shfl_xor(s2, 1);  s2 += __shfl_xor(s2, 2);
        sq2 += __shfl_xor(sq2, 1); sq2 += __shfl_xor(sq2, 2);
        const float m2 = s2 * (1.f/128.f);
        const float rs2 = rsqrtf(sq2*(1.f/128.f) - m2*m2 + 1e-5f);
        #pragma unroll
        for (int g = 0; g < 4; g++) {
          const float4 ga = *(const float4*)(g2 + lk + g*8);
          const float4 gb = *(const float4*)(g2 + lk + g*8 + 4);
          const float4 ba = *(const float4*)(b2 + lk + g*8);
          const float4 bbv= *(const float4*)(b2 + lk + g*8 + 4);
          ushort8v pa;
          pa[0] = f2bf((av[2*g].x   - m2)*rs2*ga.x + ba.x);
          pa[1] = f2bf((av[2*g].y   - m2)*rs2*ga.y + ba.y);
          pa[2] = f2bf((av[2*g].z   - m2)*rs2*ga.z + ba.z);
          pa[3] = f2bf((av[2*g].w   - m2)*rs2*ga.w + ba.w);
          pa[4] = f2bf((av[2*g+1].x - m2)*rs2*gb.x + bbv.x);
          pa[5] = f2bf((av[2*g+1].y - m2)*rs2*gb.y + bbv.y);
          pa[6] = f2bf((av[2*g+1].z - m2)*rs2*gb.z + bbv.z);
          pa[7] = f2bf((av[2*g+1].w - m2)*rs2*gb.w + bbv.w);
          *(ushort8v*)&Atile[lr][lk + g*8] = pa;
        }
      } else {
        const ushort8v zz = {};
        #pragma unroll
        for (int g = 0; g < 4; g++) *(ushort8v*)&Atile[lr][lk + g*8] = zz;
      }
    }
  }
  __syncthreads();

  // --- P2a: registerize A fragments (3 m-tiles x 4 k-slices) ---
  short8 af[3][4];
  #pragma unroll
  for (int mt = 0; mt < 3; mt++)
    #pragma unroll
    for (int ks = 0; ks < 4; ks++)
      af[mt][ks] = *(const short8*)&Atile[mt*16 + l16][ks*32 + quad*8];
  __syncthreads();   // Atile dead -> Wch may overwrite

  // --- P2b: in_proj GEMM, 6 N-chunks of 64 (4 u-chunks + 2 z-chunks) ---
  for (int nc = 0; nc < 6; nc++) {
    const int colbase = (nc < 4) ? nc*64 : 256 + eb*128 + (nc-4)*64;
    {
      const int r = tid >> 2, seg = (tid & 3) * 32;
      const float* wp = in_w + (size_t)(colbase + r)*DD + seg;
      #pragma unroll
      for (int g = 0; g < 4; g++) {
        const float4 v0 = *(const float4*)(wp + g*8);
        const float4 v1 = *(const float4*)(wp + g*8 + 4);
        *(ushort8v*)&Wch[r][seg + g*8] = pack8(v0, v1);
      }
    }
    __syncthreads();
    floatx4 acc[3] = {};
    #pragma unroll
    for (int ks = 0; ks < 4; ks++) {
      short8 bv = *(const short8*)&Wch[wave*16 + l16][ks*32 + quad*8];
      #pragma unroll
      for (int mt = 0; mt < 3; mt++)
        acc[mt] = __builtin_amdgcn_mfma_f32_16x16x32_bf16(af[mt][ks], bv, acc[mt], 0, 0, 0);
    }
    const int coll = wave*16 + l16;
    #pragma unroll
    for (int mt = 0; mt < 3; mt++)
      #pragma unroll
      for (int rr = 0; rr < 4; rr++) {
        const int m = mt*16 + quad*4 + rr;
        if (nc < 4) {
          if (m < 35) ubuf[m][nc*64 + coll] = acc[mt][rr];
        } else {
          if (m >= 3 && m < 35) {
            const float v = acc[mt][rr];
            gate[(size_t)(t0 + m - 3)*ED + (colbase - 256) + coll] =
                v / (1.f + __expf(-v));
          }
        }
      }
    __syncthreads();
  }

  // --- P3: causal depthwise conv + silu; thread = channel, 32 tokens ---
  {
    const int ch = tid;
    const float4 w = *(const float4*)(cw + ch*4);
    const float cbe = cb[ch];
    float h0 = ubuf[0][ch], h1 = ubuf[1][ch], h2 = ubuf[2][ch];
    const bool own = (ch >> 7) == eb;
    #pragma unroll
    for (int i = 0; i < LC; i++) {
      const float cur = ubuf[3+i][ch];
      const float a = cbe + h0*w.x + h1*w.y + h2*w.z + cur*w.w;
      const float s = a / (1.f + __expf(-a));
      As[i][ch] = f2bf(s);
      if (own) {
        sus[i][ch & 127] = s;
        uc[(size_t)(t0+i)*ED + ch] = s;
      }
      h0 = h1; h1 = h2; h2 = cur;
    }
  }
  __syncthreads();   // conv done (ubuf dead); As complete

  // --- P3.5: stage xproj weights Bs[64][264] bf16 (rows >= 40 zeroed) ---
  #pragma unroll
  for (int p = 0; p < 8; p++) {
    const int idx = p*256 + tid;           // 2048 groups of 8 shorts
    const int row = idx >> 5;
    const int col = (idx & 31) * 8;
    ushort8v v = {};
    if (row < 40) {
      const float4 v0 = *(const float4*)(xpw + (size_t)row*ED + col);
      const float4 v1 = *(const float4*)(xpw + (size_t)row*ED + col + 4);
      v = pack8(v0, v1);
    }
    *(ushort8v*)&Bs[row][col] = v;
  }
  __syncthreads();

  // --- P4: xproj MFMA: M=32, N=64(pad 40), K=256 ---
  {
    const int mi = (wave & 1) * 16;
    const int j0 = (wave >> 1) * 2;
    floatx4 acc[2] = {};
    #pragma unroll
    for (int ks = 0; ks < 8; ks++) {
      const int ko = ks*32 + quad*8;
      short8 a  = *(const short8*)&As[mi + l16][ko];
      short8 b0 = *(const short8*)&Bs[j0*16 +      l16][ko];
      short8 b1 = *(const short8*)&Bs[j0*16 + 16 + l16][ko];
      acc[0] = __builtin_amdgcn_mfma_f32_16x16x32_bf16(a, b0, acc[0], 0, 0, 0);
      acc[1] = __builtin_amdgcn_mfma_f32_16x16x32_bf16(a, b1, acc[1], 0, 0, 0);
    }
    __syncthreads();   // As/Bs reads done; sdbc may alias Bs, sdel may alias As
    #pragma unroll
    for (int f = 0; f < 2; f++) {
      const int n = (j0 + f)*16 + l16;
      #pragma unroll
      for (int r = 0; r < 4; r++) {
        const int m = mi + quad*4 + r;
        if (n < 40) {
          sdbc[m][n] = acc[f][r];
          if (eb == 0) dbc[(size_t)(t0 + m)*40 + n] = acc[f][r];
        }
      }
    }
  }
  __syncthreads();

  // --- P5: delta = softplus(dt @ dt_w^T + dt_b) for own 128 channels ---
  const int e_loc = tid >> 1;
  const int half  = tid & 1;
  const int e     = eb*128 + e_loc;
  {
    const float4 w0 = *(const float4*)(dtw + e*RR);
    const float4 w1 = *(const float4*)(dtw + e*RR + 4);
    const float db = dtb[e];
    #pragma unroll 4
    for (int i = 0; i < 16; i++) {
      const int t = half*16 + i;
      const float a = db
          + sdbc[t][0]*w0.x + sdbc[t][1]*w0.y + sdbc[t][2]*w0.z + sdbc[t][3]*w0.w
          + sdbc[t][4]*w1.x + sdbc[t][5]*w1.y + sdbc[t][6]*w1.z + sdbc[t][7]*w1.w;
      const float d = (a > 20.f) ? a : log1pf(__expf(a));
      sdel[t][e_loc] = d;
      delta[(size_t)(t0+t)*ED + e] = d;
    }
  }
  __syncthreads();

  // --- P6: per-chunk scan summaries; thread owns (e, n-half) ---
  const int n0 = half * 8;
  const float4 a0 = *(const float4*)(A_log + e*NN + n0);
  const float4 a1 = *(const float4*)(A_log + e*NN + n0 + 4);
  float Aen[8] = {-__expf(a0.x)*LOG2E, -__expf(a0.y)*LOG2E,
                  -__expf(a0.z)*LOG2E, -__expf(a0.w)*LOG2E,
                  -__expf(a1.x)*LOG2E, -__expf(a1.y)*LOG2E,
                  -__expf(a1.z)*LOG2E, -__expf(a1.w)*LOG2E};
  float h[8] = {};
  float sumd = 0.f;
  for (int i = 0; i < LC; i++) {
    const float dv = sdel[i][e_loc];
    const float du = dv * sus[i][e_loc];
    const float4 B0 = *(const float4*)&sdbc[i][RR + n0];
    const float4 B1 = *(const float4*)&sdbc[i][RR + n0 + 4];
    const float Bv[8] = {B0.x,B0.y,B0.z,B0.w,B1.x,B1.y,B1.z,B1.w};
    sumd += dv;
    #pragma unroll
    for (int j = 0; j < 8; j++)
      h[j] = exp2_fast(dv * Aen[j])*h[j] + Bv[j]*du;
  }
  const size_t base = (((size_t)c*BB + b)*ED + e)*NN + n0;
  *(float4*)(cA + base)     = make_float4(exp2_fast(sumd*Aen[0]), exp2_fast(sumd*Aen[1]),
                                          exp2_fast(sumd*Aen[2]), exp2_fast(sumd*Aen[3]));
  *(float4*)(cA + base + 4) = make_float4(exp2_fast(sumd*Aen[4]), exp2_fast(sumd*Aen[5]),
                                          exp2_fast(sumd*Aen[6]), exp2_fast(sumd*Aen[7]));
  *(float4*)(cH + base)     = make_float4(h[0], h[1], h[2], h[3]);
  *(float4*)(cH + base + 4) = make_float4(h[4], h[5], h[6], h[7]);
}

// ---------------------------------------------------------------------------
// Scan phase 2 (4-way segmented): each (b,e,n) scan of NC=128 chunks is split
// across 4 threads (32 chunks each). Pass 1: per-segment affine summary
// (Aprod, Hseg); shfl-compose boundary states; pass 2: replay + write
// exclusive prefix in-place into cA. Serial chain 128 -> ~64.
// 128 blocks x 256 threads.
// ---------------------------------------------------------------------------
__global__ __launch_bounds__(256) void scan2p_k(float* __restrict__ cA,
    const float* __restrict__ cH) {
  const int gt = blockIdx.x*256 + threadIdx.x;  // [0, 4*BB*ED*NN)
  const int scan = gt >> 2;                     // [0, BB*ED*NN)
  const int seg  = gt & 3;
  const int lane = threadIdx.x & 63;
  const int lb   = lane & ~3;
  const int b = scan >> 12;
  const size_t base = (size_t)b*ED*NN + (scan & 4095);
  const int c0 = seg * 32;

  // pass 1: segment summary (Aprod, Hseg) over own 32 chunks
  float ap = 1.f, hs = 0.f;
  for (int g = 0; g < 2; g++) {
    float av[16], hv[16];
    #pragma unroll
    for (int i = 0; i < 16; i++) {
      const size_t idx = (size_t)(c0 + g*16 + i)*(BB*ED*NN) + base;
      av[i] = cA[idx]; hv[i] = cH[idx];
    }
    #pragma unroll
    for (int i = 0; i < 16; i++) {
      hs = av[i]*hs + hv[i];
      ap *= av[i];
    }
  }
  // compose boundary state for this segment (h0 at chunk c0)
  float h = 0.f;
  #pragma unroll
  for (int k = 0; k < 3; k++) {
    const float ak = __shfl(ap, lb + k);
    const float hk = __shfl(hs, lb + k);
    if (seg > k) h = ak*h + hk;
  }
  // pass 2: replay + write exclusive prefix
  for (int g = 0; g < 2; g++) {
    float av[16], hv[16];
    #pragma unroll
    for (int i = 0; i < 16; i++) {
      const size_t idx = (size_t)(c0 + g*16 + i)*(BB*ED*NN) + base;
      av[i] = cA[idx]; hv[i] = cH[idx];
    }
    #pragma unroll
    for (int i = 0; i < 16; i++) {
      const size_t idx = (size_t)(c0 + g*16 + i)*(BB*ED*NN) + base;
      cA[idx] = h;
      h = av[i]*h + hv[i];
    }
  }
}

// ---------------------------------------------------------------------------
// Mega-tail v7: 1024 threads (16 waves = 4 waves/SIMD -> 2x the latency
// hiding of v6 in every phase). Replay split (e, n-quarter) with h[4] per
// thread (half the serial VALU of v6); join via 2x shfl_xor. All MFMA /
// staging / LN phases re-indexed for 16 waves.
// ---------------------------------------------------------------------------
__global__ __launch_bounds__(1024) void tail7_k(
    const float* __restrict__ gate, const float* __restrict__ delta,
    const float* __restrict__ uc, const float* __restrict__ dbc,
    const float* __restrict__ cP, const float* __restrict__ A_log,
    const float* __restrict__ Dpv, const float* __restrict__ x,
    const float* __restrict__ g1, const float* __restrict__ b1,
    const float* __restrict__ out_w, const float* __restrict__ fc1_w,
    const float* __restrict__ fc1_b, const float* __restrict__ fc2_w,
    const float* __restrict__ fc2_b, float* __restrict__ out) {
  __shared__ __align__(16) unsigned short BigW[34816];  // 69.6 KB: Wo/W1/W2
  __shared__ __align__(16) unsigned short Au[32][264];  // y -> hln -> h (bf16)
  __shared__ float xs[32][132];                         // xnew tile fp32
  __shared__ float sbc[32][32];                         // B/C rows (LDS bcast)

  const int c = blockIdx.x, b = blockIdx.y;
  const int t0 = b*LL + c*LC;
  const int tid = threadIdx.x;
  const int wave = tid >> 6, lane = tid & 63;
  const int quad = lane >> 4, l16 = lane & 15;

  // --- stage B/C (32 tokens x 32 floats) -> sbc, one coalesced round ---
  if (tid < 256) {
    const int row = tid >> 3, c4 = (tid & 7) * 4;
    *(float4*)&sbc[row][c4] = *(const float4*)(dbc + (size_t)(t0 + row)*40 + RR + c4);
  }
  __syncthreads();

  // --- stage out_w (128x256) -> BigW bf16, stride 264 (overlaps replay) ---
  {
    const int r = tid >> 3, k0 = (tid & 7) * 32;
    const float* wp = out_w + (size_t)r*ED + k0;
    #pragma unroll
    for (int g = 0; g < 4; g++) {
      const float4 v0 = *(const float4*)(wp + g*8);
      const float4 v1 = *(const float4*)(wp + g*8 + 4);
      *(ushort8v*)&BigW[(size_t)r*264 + k0 + g*8] = pack8(v0, v1);
    }
  }

  // --- scan replay: thread = (e, n-quarter), h[4], 8-deep prefetch ---
  {
    const int e = tid >> 2, q = tid & 3;
    const int n0 = q * 4;
    float Aen[4], h[4];
    {
      const float4 a0 = *(const float4*)(A_log + e*NN + n0);
      Aen[0]=-__expf(a0.x)*LOG2E; Aen[1]=-__expf(a0.y)*LOG2E;
      Aen[2]=-__expf(a0.z)*LOG2E; Aen[3]=-__expf(a0.w)*LOG2E;
      const float4 h0 = *(const float4*)(cP + (((size_t)c*BB + b)*ED + e)*NN + n0);
      h[0]=h0.x; h[1]=h0.y; h[2]=h0.z; h[3]=h0.w;
    }
    const float Dpe = Dpv[e];
    float pd[8], pu[8], pg[8];
    #pragma unroll
    for (int i = 0; i < 8; i++) {
      pd[i] = delta[(size_t)(t0+i)*ED + e];
      pu[i] = uc[(size_t)(t0+i)*ED + e];
      pg[i] = gate[(size_t)(t0+i)*ED + e];
    }
    for (int g4 = 0; g4 < 4; g4++) {
      float cd[8], cu[8], cg[8];
      #pragma unroll
      for (int i = 0; i < 8; i++) { cd[i]=pd[i]; cu[i]=pu[i]; cg[i]=pg[i]; }
      if (g4 < 3) {
        const int tn = t0 + (g4+1)*8;
        #pragma unroll
        for (int i = 0; i < 8; i++) {
          pd[i] = delta[(size_t)(tn+i)*ED + e];
          pu[i] = uc[(size_t)(tn+i)*ED + e];
          pg[i] = gate[(size_t)(tn+i)*ED + e];
        }
      }
      #pragma unroll
      for (int i = 0; i < 8; i++) {
        const int t = g4*8 + i;
        const float dv = cd[i];
        const float uv = cu[i];
        const float du = dv * uv;
        const float4 B0 = *(const float4*)&sbc[t][n0];
        const float4 C0 = *(const float4*)&sbc[t][16 + n0];
        const float Bv[4] = {B0.x,B0.y,B0.z,B0.w};
        const float Cv[4] = {C0.x,C0.y,C0.z,C0.w};
        float part = 0.f;
        #pragma unroll
        for (int j = 0; j < 4; j++) {
          h[j] = exp2_fast(dv * Aen[j])*h[j] + Bv[j]*du;
          part += h[j]*Cv[j];
        }
        part += __shfl_xor(part, 1);          // join 4 n-quarters (same e)
        part += __shfl_xor(part, 2);
        if (q == 0)
          Au[t][e] = f2bf((part + uv*Dpe) * cg[i]);
      }
    }
  }
  __syncthreads();

  // --- out_proj MFMA: M=32, N=128, K=256; 16 waves, 1 tile each ---
  {
    const int mi = (wave & 1) * 16;
    const int wn = (wave >> 1) * 16;
    floatx4 acc = {};
    #pragma unroll
    for (int ks = 0; ks < 8; ks++) {
      const int ko = ks*32 + quad*8;
      short8 a  = *(const short8*)&Au[mi + l16][ko];
      short8 bv = *(const short8*)&BigW[(size_t)(wn + l16)*264 + ko];
      acc = __builtin_amdgcn_mfma_f32_16x16x32_bf16(a, bv, acc, 0, 0, 0);
    }
    const int n = wn + l16;
    #pragma unroll
    for (int r = 0; r < 4; r++) {
      const int m = mi + quad*4 + r;
      xs[m][n] = acc[r] + x[(size_t)(t0 + m)*DD + n];
    }
  }
  __syncthreads();

  // --- norm1 per row (16 threads/row, 8 elems each) -> hln into Au[., 0:128]
  if (tid < 512) {
    const int lr = tid >> 4, le = (tid & 15) * 8;
    float vv[8];
    float s = 0.f, sq = 0.f;
    #pragma unroll
    for (int i = 0; i < 8; i++) {
      vv[i] = xs[lr][le + i];
      s += vv[i]; sq += vv[i]*vv[i];
    }
    s += __shfl_xor(s, 1);  s += __shfl_xor(s, 2);
    s += __shfl_xor(s, 4);  s += __shfl_xor(s, 8);
    sq += __shfl_xor(sq, 1); sq += __shfl_xor(sq, 2);
    sq += __shfl_xor(sq, 4); sq += __shfl_xor(sq, 8);
    const float mean = s * (1.f/128.f);
    const float rs = rsqrtf(sq*(1.f/128.f) - mean*mean + 1e-5f);
    ushort8v p;
    #pragma unroll
    for (int i = 0; i < 8; i++)
      p[i] = f2bf((vv[i] - mean)*rs*g1[le + i] + b1[le + i]);
    *(ushort8v*)&Au[lr][le] = p;
  }
  // --- stage fc1_w (256x128) -> BigW bf16, stride 136 ---
  {
    const int r = tid >> 2, k0 = (tid & 3) * 32;
    const float* wp = fc1_w + (size_t)r*DD + k0;
    #pragma unroll
    for (int g = 0; g < 4; g++) {
      const float4 v0 = *(const float4*)(wp + g*8);
      const float4 v1 = *(const float4*)(wp + g*8 + 4);
      *(ushort8v*)&BigW[(size_t)r*136 + k0 + g*8] = pack8(v0, v1);
    }
  }
  __syncthreads();

  // --- fc1 MFMA: M=32, N=256, K=128; 16 waves x 2 n-tiles; gelu -> Au ---
  {
    const int mi = (wave & 1) * 16;
    const int wn = (wave >> 1) * 32;
    floatx4 acc[2] = {};
    #pragma unroll
    for (int ks = 0; ks < 4; ks++) {
      const int ko = ks*32 + quad*8;
      short8 a  = *(const short8*)&Au[mi + l16][ko];
      short8 b0 = *(const short8*)&BigW[(size_t)(wn +      l16)*136 + ko];
      short8 b1 = *(const short8*)&BigW[(size_t)(wn + 16 + l16)*136 + ko];
      acc[0] = __builtin_amdgcn_mfma_f32_16x16x32_bf16(a, b0, acc[0], 0, 0, 0);
      acc[1] = __builtin_amdgcn_mfma_f32_16x16x32_bf16(a, b1, acc[1], 0, 0, 0);
    }
    __syncthreads();   // all hln reads (Au) + fc1_w reads (BigW) done
    #pragma unroll
    for (int f = 0; f < 2; f++) {
      const int n = wn + f*16 + l16;
      const float bn = fc1_b[n];
      #pragma unroll
      for (int r = 0; r < 4; r++) {
        const int m = mi + quad*4 + r;
        float v = acc[f][r] + bn;
        v = 0.5f*v*(1.f + erff(v*0.70710678118f));
        Au[m][n] = f2bf(v);
      }
    }
  }
  // --- stage fc2_w (128x256) -> BigW bf16, stride 264 ---
  {
    const int r = tid >> 3, k0 = (tid & 7) * 32;
    const float* wp = fc2_w + (size_t)r*HH + k0;
    #pragma unroll
    for (int g = 0; g < 4; g++) {
      const float4 v0 = *(const float4*)(wp + g*8);
      const float4 v1 = *(const float4*)(wp + g*8 + 4);
      *(ushort8v*)&BigW[(size_t)r*264 + k0 + g*8] = pack8(v0, v1);
    }
  }
  __syncthreads();

  // --- fc2 MFMA: M=32, N=128, K=256; 16 waves, 1 tile each; -> out ---
  {
    const int mi = (wave & 1) * 16;
    const int wn = (wave >> 1) * 16;
    floatx4 acc = {};
    #pragma unroll
    for (int ks = 0; ks < 8; ks++) {
      const int ko = ks*32 + quad*8;
      short8 a  = *(const short8*)&Au[mi + l16][ko];
      short8 bv = *(const short8*)&BigW[(size_t)(wn + l16)*264 + ko];
      acc = __builtin_amdgcn_mfma_f32_16x16x32_bf16(a, bv, acc, 0, 0, 0);
    }
    const int n = wn + l16;
    const float bn = fc2_b[n];
    #pragma unroll
    for (int r = 0; r < 4; r++) {
      const int m = mi + quad*4 + r;
      out[(size_t)(t0 + m)*DD + n] = acc[r] + bn + xs[m][n];
    }
  }
}

// ---------------------------------------------------------------------------
extern "C" void kernel_launch(void* const* d_in, const int* in_sizes, int n_in,
                              void* d_out, int out_size, void* d_ws, size_t ws_size,
                              hipStream_t stream) {
  const float* x      = (const float*)d_in[0];
  const float* n1g    = (const float*)d_in[1];
  const float* n1b    = (const float*)d_in[2];
  const float* ing    = (const float*)d_in[3];
  const float* inb    = (const float*)d_in[4];
  const float* in_w   = (const float*)d_in[5];
  const float* conv_w = (const float*)d_in[6];
  const float* conv_b = (const float*)d_in[7];
  const float* xproj_w= (const float*)d_in[8];
  const float* dt_w   = (const float*)d_in[9];
  const float* dt_b   = (const float*)d_in[10];
  const float* A_log  = (const float*)d_in[11];
  const float* Dpv    = (const float*)d_in[12];
  const float* out_w  = (const float*)d_in[13];
  const float* fc1_w  = (const float*)d_in[14];
  const float* fc1_b  = (const float*)d_in[15];
  const float* fc2_w  = (const float*)d_in[16];
  const float* fc2_b  = (const float*)d_in[17];
  float* out = (float*)d_out;

  // Workspace (~35 MB)
  float* ws    = (float*)d_ws;
  float* uc    = ws;                          // [NT,256]
  float* dbc   = uc    + (size_t)NT*ED;       // [NT,40]
  float* delta = dbc   + (size_t)NT*40;       // [NT,256]
  float* gate  = delta + (size_t)NT*ED;       // [NT,256]  silu(z)
  float* cA    = gate  + (size_t)NT*ED;       // [NC,B,ED,N]
  float* cH    = cA    + (size_t)NC*BB*ED*NN;

  // 1) fused LN+in_proj GEMM+conv+xproj+delta+summaries
  scan1g_k<<<dim3(2, NC, BB), 256, 0, stream>>>(x, n1g, n1b, ing, inb, in_w,
                                                conv_w, conv_b, xproj_w, dt_w, dt_b,
                                                A_log, uc, dbc, delta, gate, cA, cH);
  // 2) inter-chunk prefix (4-way segmented)
  scan2p_k<<<(4*BB*ED*NN)/256, 256, 0, stream>>>(cA, cH);
  // 3) scan replay + gate + out_proj + LN + MLP + residuals -> out
  tail7_k<<<dim3(NC, BB), 1024, 0, stream>>>(gate, delta, uc, dbc, cA, A_log, Dpv,
                                             x, n1g, n1b, out_w, fc1_w, fc1_b,
                                             fc2_w, fc2_b, out);
}

// Round 5
// 164.256 us; speedup vs baseline: 1.0107x; 1.0107x over previous
//
#include <hip/hip_runtime.h>
#include <hip/hip_bf16.h>
#include <math.h>

// Problem constants (match reference)
#define BB 2
#define LL 4096
#define DD 128
#define ED 256
#define NN 16
#define KK 4
#define RR 8
#define HH 256
#define NT (BB*LL)          // 8192 tokens
#define NC 128              // chunks for scan
#define LC 32               // chunk length (NC*LC == LL)

#define LOG2E 1.4426950408889634f

typedef __attribute__((ext_vector_type(8))) short short8;
typedef __attribute__((ext_vector_type(8))) unsigned short ushort8v;
typedef __attribute__((ext_vector_type(4))) float floatx4;

__device__ __forceinline__ unsigned short f2bf(float f) {
  unsigned int b = __builtin_bit_cast(unsigned int, f);
  b += 0x7FFFu + ((b >> 16) & 1u);           // round-to-nearest-even
  return (unsigned short)(b >> 16);
}

__device__ __forceinline__ float exp2_fast(float x) {
#if __has_builtin(__builtin_amdgcn_exp2f)
  return __builtin_amdgcn_exp2f(x);
#else
  return exp2f(x);
#endif
}

__device__ __forceinline__ ushort8v pack8(const float4& v0, const float4& v1) {
  ushort8v p;
  p[0]=f2bf(v0.x); p[1]=f2bf(v0.y); p[2]=f2bf(v0.z); p[3]=f2bf(v0.w);
  p[4]=f2bf(v1.x); p[5]=f2bf(v1.y); p[6]=f2bf(v1.z); p[7]=f2bf(v1.w);
  return p;
}

// ---------------------------------------------------------------------------
// scan1h: one 512-thread block per (c,b) chunk — NO eb duplication (r4's
// scan1g pair did LN 2x, u-GEMM 1.5x, conv 2x). Pipeline per block:
//   P1 double-LN (35 rows + 13 zero pad) -> Atile bf16
//   P2 in_proj GEMM as 8 chunks of 64 cols (W reg-prefetched); u-chunks 0-3
//      each immediately followed by conv+silu of those 64 channels
//      (ubuf is only [35][65]); z-chunks 4-7 write gate=silu(z) directly
//   P3.5 stage xproj W (40 rows, no pad: last MFMA tile overlaps at jn=24)
//   P4 xproj MFMA M=32 N=40 K=256 (6 waves)
//   P5+P6 merged: delta recomputed per n-half (no sdel buffer) + chunk scan
// LDS 78.0 KB overlaid:
//   [0    ,16896) Atile[48][136]u16 (P1-P2a) / As[32][264]u16 (P2conv-P4)
//   [16896,38016) Wch[64][136]u16 (P2) / Bs[40][264]u16 (P3.5-P4)
//   [38016,47120) ubuf[35][65]f32 (P2) / sdbc[32][40]f32 (P4+)
//   [47120,79888) sus[32][256]f32 (P2conv+)
// ---------------------------------------------------------------------------
__global__ __launch_bounds__(512) void scan1h_k(
    const float* __restrict__ x,
    const float* __restrict__ g1, const float* __restrict__ b1,
    const float* __restrict__ g2, const float* __restrict__ b2,
    const float* __restrict__ in_w,
    const float* __restrict__ cw, const float* __restrict__ cb,
    const float* __restrict__ xpw,
    const float* __restrict__ dtw, const float* __restrict__ dtb,
    const float* __restrict__ A_log,
    float* __restrict__ uc, float* __restrict__ dbc,
    float* __restrict__ delta, float* __restrict__ gate,
    float* __restrict__ cA, float* __restrict__ cH) {
  __shared__ __align__(16) unsigned char SM[79888];
  auto Atile = reinterpret_cast<unsigned short(*)[136]>(SM);
  auto As    = reinterpret_cast<unsigned short(*)[264]>(SM);
  auto Wch   = reinterpret_cast<unsigned short(*)[136]>(SM + 16896);
  auto Bs    = reinterpret_cast<unsigned short(*)[264]>(SM + 16896);
  auto ubuf  = reinterpret_cast<float(*)[65]>(SM + 38016);
  auto sdbc  = reinterpret_cast<float(*)[40]>(SM + 38016);
  auto sus   = reinterpret_cast<float(*)[256]>(SM + 47120);

  const int c = blockIdx.x, b = blockIdx.y;
  const int tid = threadIdx.x;
  const int t0 = b*LL + c*LC;
  const int wave = tid >> 6, lane = tid & 63;
  const int quad = lane >> 4, l16 = lane & 15;

  // --- P1: double-LN of x rows (t0-3 .. t0+31) -> Atile bf16 [48][136] ---
  // 4 threads/row (same reduction tree as r3/r4 -> bit-identical)
  {
    const int lr = tid >> 2, lk = (tid & 3) * 32;
    if (lr < 48) {
      if (lr < 35 && !(c == 0 && lr < 3)) {
        const float* Ap = x + (size_t)(t0 - 3 + lr)*DD + lk;
        float4 av[8];
        float s = 0.f, sq = 0.f;
        #pragma unroll
        for (int g = 0; g < 8; g++) {
          av[g] = *(const float4*)(Ap + g*4);
          s  += av[g].x + av[g].y + av[g].z + av[g].w;
          sq += av[g].x*av[g].x + av[g].y*av[g].y + av[g].z*av[g].z + av[g].w*av[g].w;
        }
        s += __shfl_xor(s, 1);  s += __shfl_xor(s, 2);
        sq += __shfl_xor(sq, 1); sq += __shfl_xor(sq, 2);
        const float m1 = s * (1.f/128.f);
        const float rs1 = rsqrtf(sq*(1.f/128.f) - m1*m1 + 1e-5f);
        float s2 = 0.f, sq2 = 0.f;
        #pragma unroll
        for (int g = 0; g < 8; g++) {
          const float4 gg = *(const float4*)(g1 + lk + g*4);
          const float4 bb = *(const float4*)(b1 + lk + g*4);
          av[g].x = (av[g].x - m1)*rs1*gg.x + bb.x;
          av[g].y = (av[g].y - m1)*rs1*gg.y + bb.y;
          av[g].z = (av[g].z - m1)*rs1*gg.z + bb.z;
          av[g].w = (av[g].w - m1)*rs1*gg.w + bb.w;
          s2  += av[g].x + av[g].y + av[g].z + av[g].w;
          sq2 += av[g].x*av[g].x + av[g].y*av[g].y + av[g].z*av[g].z + av[g].w*av[g].w;
        }
        s2 += __shfl_xor(s2, 1);  s2 += __shfl_xor(s2, 2);
        sq2 += __shfl_xor(sq2, 1); sq2 += __shfl_xor(sq2, 2);
        const float m2 = s2 * (1.f/128.f);
        const float rs2 = rsqrtf(sq2*(1.f/128.f) - m2*m2 + 1e-5f);
        #pragma unroll
        for (int g = 0; g < 4; g++) {
          const float4 ga = *(const float4*)(g2 + lk + g*8);
          const float4 gb = *(const float4*)(g2 + lk + g*8 + 4);
          const float4 ba = *(const float4*)(b2 + lk + g*8);
          const float4 bbv= *(const float4*)(b2 + lk + g*8 + 4);
          ushort8v pa;
          pa[0] = f2bf((av[2*g].x   - m2)*rs2*ga.x + ba.x);
          pa[1] = f2bf((av[2*g].y   - m2)*rs2*ga.y + ba.y);
          pa[2] = f2bf((av[2*g].z   - m2)*rs2*ga.z + ba.z);
          pa[3] = f2bf((av[2*g].w   - m2)*rs2*ga.w + ba.w);
          pa[4] = f2bf((av[2*g+1].x - m2)*rs2*gb.x + bbv.x);
          pa[5] = f2bf((av[2*g+1].y - m2)*rs2*gb.y + bbv.y);
          pa[6] = f2bf((av[2*g+1].z - m2)*rs2*gb.z + bbv.z);
          pa[7] = f2bf((av[2*g+1].w - m2)*rs2*gb.w + bbv.w);
          *(ushort8v*)&Atile[lr][lk + g*8] = pa;
        }
      } else {
        const ushort8v zz = {};
        #pragma unroll
        for (int g = 0; g < 4; g++) *(ushort8v*)&Atile[lr][lk + g*8] = zz;
      }
    }
  }
  __syncthreads();

  // --- P2a: registerize A fragments. Wave w: n-tile (w&3); m-tiles:
  // w<4 -> {0,2}, w>=4 -> {1}. ---
  const int nt_w = wave & 3;
  const int mlo  = (wave < 4) ? 0 : 16;
  short8 af0[4], af1[4];
  #pragma unroll
  for (int ks = 0; ks < 4; ks++) {
    af0[ks] = *(const short8*)&Atile[mlo + l16][ks*32 + quad*8];
    if (wave < 4) af1[ks] = *(const short8*)&Atile[32 + l16][ks*32 + quad*8];
  }
  __syncthreads();   // Atile dead -> Wch/As may overwrite

  // --- P2b: in_proj GEMM, 8 chunks of 64 cols; conv fused after u-chunks ---
  {
    const int wr = tid >> 3;            // W staging row 0..63
    const int wseg = (tid & 7) * 16;    // 16 floats
    float4 wv[4];
    #pragma unroll
    for (int g = 0; g < 4; g++)
      wv[g] = *(const float4*)(in_w + (size_t)wr*DD + wseg + g*4);
    for (int nc = 0; nc < 8; nc++) {
      *(ushort8v*)&Wch[wr][wseg]     = pack8(wv[0], wv[1]);
      *(ushort8v*)&Wch[wr][wseg + 8] = pack8(wv[2], wv[3]);
      __syncthreads();   // Wch ready; prior conv's ubuf reads done
      if (nc < 7) {
        const float* wp = in_w + (size_t)((nc+1)*64 + wr)*DD + wseg;
        #pragma unroll
        for (int g = 0; g < 4; g++) wv[g] = *(const float4*)(wp + g*4);
      }
      floatx4 acc0 = {}, acc1 = {};
      #pragma unroll
      for (int ks = 0; ks < 4; ks++) {
        short8 bv = *(const short8*)&Wch[nt_w*16 + l16][ks*32 + quad*8];
        acc0 = __builtin_amdgcn_mfma_f32_16x16x32_bf16(af0[ks], bv, acc0, 0, 0, 0);
        if (wave < 4)
          acc1 = __builtin_amdgcn_mfma_f32_16x16x32_bf16(af1[ks], bv, acc1, 0, 0, 0);
      }
      const int coll = nt_w*16 + l16;
      if (nc < 4) {
        #pragma unroll
        for (int rr = 0; rr < 4; rr++)
          ubuf[mlo + quad*4 + rr][coll] = acc0[rr];
        if (wave < 4) {
          #pragma unroll
          for (int rr = 0; rr < 4; rr++) {
            const int m1 = 32 + quad*4 + rr;
            if (m1 < 35) ubuf[m1][coll] = acc1[rr];
          }
        }
      } else {
        const int gcol = (nc-4)*64 + coll;
        #pragma unroll
        for (int rr = 0; rr < 4; rr++) {
          const int m0 = mlo + quad*4 + rr;
          if (m0 >= 3) {
            const float v = acc0[rr];
            gate[(size_t)(t0 + m0 - 3)*ED + gcol] = v / (1.f + __expf(-v));
          }
        }
        if (wave < 4) {
          #pragma unroll
          for (int rr = 0; rr < 4; rr++) {
            const int m1 = 32 + quad*4 + rr;
            if (m1 < 35) {
              const float v = acc1[rr];
              gate[(size_t)(t0 + m1 - 3)*ED + gcol] = v / (1.f + __expf(-v));
            }
          }
        }
      }
      __syncthreads();   // ubuf ready / Wch reads done
      if (nc < 4) {
        // conv+silu for channels nc*64 .. nc*64+63; thread=(ch,4-token grp)
        const int chl = tid & 63, tg = tid >> 6;
        const int ch = nc*64 + chl;
        const float4 w = *(const float4*)(cw + ch*4);
        const float cbe = cb[ch];
        float v0 = ubuf[tg*4 + 0][chl];
        float v1 = ubuf[tg*4 + 1][chl];
        float v2 = ubuf[tg*4 + 2][chl];
        #pragma unroll
        for (int k = 0; k < 4; k++) {
          const float cur = ubuf[tg*4 + 3 + k][chl];
          const float a = cbe + v0*w.x + v1*w.y + v2*w.z + cur*w.w;
          const float s = a / (1.f + __expf(-a));
          const int i = tg*4 + k;
          As[i][ch] = f2bf(s);
          sus[i][ch] = s;
          uc[(size_t)(t0+i)*ED + ch] = s;
          v0 = v1; v1 = v2; v2 = cur;
        }
      }
    }
  }
  __syncthreads();   // all conv done; As/sus complete; Wch dead

  // --- P3.5: stage xproj weights Bs[40][264] (real rows only) ---
  #pragma unroll
  for (int p = 0; p < 3; p++) {
    const int idx = p*512 + tid;           // < 1280 = 40 rows x 32 granules
    if (idx < 1280) {
      const int row = idx >> 5;
      const int col = (idx & 31) * 8;
      const float4 v0 = *(const float4*)(xpw + (size_t)row*ED + col);
      const float4 v1 = *(const float4*)(xpw + (size_t)row*ED + col + 4);
      *(ushort8v*)&Bs[row][col] = pack8(v0, v1);
    }
  }
  __syncthreads();

  // --- P4: xproj MFMA M=32, N=40, K=256; 6 waves; last tile overlaps jn=24
  {
    const int mt = wave & 1, nt = wave >> 1;
    if (wave < 6) {
      const int jn = (nt == 2) ? 24 : nt*16;
      floatx4 acc = {};
      #pragma unroll
      for (int ks = 0; ks < 8; ks++) {
        const int ko = ks*32 + quad*8;
        short8 a  = *(const short8*)&As[mt*16 + l16][ko];
        short8 bv = *(const short8*)&Bs[jn + l16][ko];
        acc = __builtin_amdgcn_mfma_f32_16x16x32_bf16(a, bv, acc, 0, 0, 0);
      }
      const int n = jn + l16;
      if (nt < 2 || l16 >= 8) {     // discard duplicated n=24..31 of last tile
        #pragma unroll
        for (int rr = 0; rr < 4; rr++) {
          const int m = mt*16 + quad*4 + rr;
          sdbc[m][n] = acc[rr];     // sdbc region (ubuf) is dead -> no alias
          dbc[(size_t)(t0 + m)*40 + n] = acc[rr];
        }
      }
    }
  }
  __syncthreads();

  // --- P5+P6 merged: delta recomputed per (e, n-half); chunk scan summary ---
  {
    const int e = tid >> 1, half = tid & 1;
    const int n0 = half * 8;
    const float4 dw0 = *(const float4*)(dtw + e*RR);
    const float4 dw1 = *(const float4*)(dtw + e*RR + 4);
    const float db = dtb[e];
    const float4 a0 = *(const float4*)(A_log + e*NN + n0);
    const float4 a1 = *(const float4*)(A_log + e*NN + n0 + 4);
    float Aen[8] = {-__expf(a0.x)*LOG2E, -__expf(a0.y)*LOG2E,
                    -__expf(a0.z)*LOG2E, -__expf(a0.w)*LOG2E,
                    -__expf(a1.x)*LOG2E, -__expf(a1.y)*LOG2E,
                    -__expf(a1.z)*LOG2E, -__expf(a1.w)*LOG2E};
    float h[8] = {};
    float sumd = 0.f;
    for (int t = 0; t < LC; t++) {
      const float4 q0 = *(const float4*)&sdbc[t][0];
      const float4 q1 = *(const float4*)&sdbc[t][4];
      const float aa = db
          + q0.x*dw0.x + q0.y*dw0.y + q0.z*dw0.z + q0.w*dw0.w
          + q1.x*dw1.x + q1.y*dw1.y + q1.z*dw1.z + q1.w*dw1.w;
      const float dv = (aa > 20.f) ? aa : log1pf(__expf(aa));
      if (half == 0) delta[(size_t)(t0+t)*ED + e] = dv;
      const float du = dv * sus[t][e];
      const float4 B0 = *(const float4*)&sdbc[t][RR + n0];
      const float4 B1 = *(const float4*)&sdbc[t][RR + n0 + 4];
      const float Bv[8] = {B0.x,B0.y,B0.z,B0.w,B1.x,B1.y,B1.z,B1.w};
      sumd += dv;
      #pragma unroll
      for (int j = 0; j < 8; j++)
        h[j] = exp2_fast(dv * Aen[j])*h[j] + Bv[j]*du;
    }
    const size_t base = (((size_t)c*BB + b)*ED + e)*NN + n0;
    *(float4*)(cA + base)     = make_float4(exp2_fast(sumd*Aen[0]), exp2_fast(sumd*Aen[1]),
                                            exp2_fast(sumd*Aen[2]), exp2_fast(sumd*Aen[3]));
    *(float4*)(cA + base + 4) = make_float4(exp2_fast(sumd*Aen[4]), exp2_fast(sumd*Aen[5]),
                                            exp2_fast(sumd*Aen[6]), exp2_fast(sumd*Aen[7]));
    *(float4*)(cH + base)     = make_float4(h[0], h[1], h[2], h[3]);
    *(float4*)(cH + base + 4) = make_float4(h[4], h[5], h[6], h[7]);
  }
}

// ---------------------------------------------------------------------------
// Scan phase 2 (4-way segmented, unchanged from round 4).
// ---------------------------------------------------------------------------
__global__ __launch_bounds__(256) void scan2p_k(float* __restrict__ cA,
    const float* __restrict__ cH) {
  const int gt = blockIdx.x*256 + threadIdx.x;  // [0, 4*BB*ED*NN)
  const int scan = gt >> 2;                     // [0, BB*ED*NN)
  const int seg  = gt & 3;
  const int lane = threadIdx.x & 63;
  const int lb   = lane & ~3;
  const int b = scan >> 12;
  const size_t base = (size_t)b*ED*NN + (scan & 4095);
  const int c0 = seg * 32;

  float ap = 1.f, hs = 0.f;
  for (int g = 0; g < 2; g++) {
    float av[16], hv[16];
    #pragma unroll
    for (int i = 0; i < 16; i++) {
      const size_t idx = (size_t)(c0 + g*16 + i)*(BB*ED*NN) + base;
      av[i] = cA[idx]; hv[i] = cH[idx];
    }
    #pragma unroll
    for (int i = 0; i < 16; i++) {
      hs = av[i]*hs + hv[i];
      ap *= av[i];
    }
  }
  float h = 0.f;
  #pragma unroll
  for (int k = 0; k < 3; k++) {
    const float ak = __shfl(ap, lb + k);
    const float hk = __shfl(hs, lb + k);
    if (seg > k) h = ak*h + hk;
  }
  for (int g = 0; g < 2; g++) {
    float av[16], hv[16];
    #pragma unroll
    for (int i = 0; i < 16; i++) {
      const size_t idx = (size_t)(c0 + g*16 + i)*(BB*ED*NN) + base;
      av[i] = cA[idx]; hv[i] = cH[idx];
    }
    #pragma unroll
    for (int i = 0; i < 16; i++) {
      const size_t idx = (size_t)(c0 + g*16 + i)*(BB*ED*NN) + base;
      cA[idx] = h;
      h = av[i]*h + hv[i];
    }
  }
}

// ---------------------------------------------------------------------------
// Mega-tail v7 (unchanged from round 4): 1024 threads, replay split
// (e, n-quarter), LDS B/C, exp2-folded Aen.
// ---------------------------------------------------------------------------
__global__ __launch_bounds__(1024) void tail7_k(
    const float* __restrict__ gate, const float* __restrict__ delta,
    const float* __restrict__ uc, const float* __restrict__ dbc,
    const float* __restrict__ cP, const float* __restrict__ A_log,
    const float* __restrict__ Dpv, const float* __restrict__ x,
    const float* __restrict__ g1, const float* __restrict__ b1,
    const float* __restrict__ out_w, const float* __restrict__ fc1_w,
    const float* __restrict__ fc1_b, const float* __restrict__ fc2_w,
    const float* __restrict__ fc2_b, float* __restrict__ out) {
  __shared__ __align__(16) unsigned short BigW[34816];  // 69.6 KB: Wo/W1/W2
  __shared__ __align__(16) unsigned short Au[32][264];  // y -> hln -> h (bf16)
  __shared__ float xs[32][132];                         // xnew tile fp32
  __shared__ float sbc[32][32];                         // B/C rows (LDS bcast)

  const int c = blockIdx.x, b = blockIdx.y;
  const int t0 = b*LL + c*LC;
  const int tid = threadIdx.x;
  const int wave = tid >> 6, lane = tid & 63;
  const int quad = lane >> 4, l16 = lane & 15;

  if (tid < 256) {
    const int row = tid >> 3, c4 = (tid & 7) * 4;
    *(float4*)&sbc[row][c4] = *(const float4*)(dbc + (size_t)(t0 + row)*40 + RR + c4);
  }
  __syncthreads();

  {
    const int r = tid >> 3, k0 = (tid & 7) * 32;
    const float* wp = out_w + (size_t)r*ED + k0;
    #pragma unroll
    for (int g = 0; g < 4; g++) {
      const float4 v0 = *(const float4*)(wp + g*8);
      const float4 v1 = *(const float4*)(wp + g*8 + 4);
      *(ushort8v*)&BigW[(size_t)r*264 + k0 + g*8] = pack8(v0, v1);
    }
  }

  {
    const int e = tid >> 2, q = tid & 3;
    const int n0 = q * 4;
    float Aen[4], h[4];
    {
      const float4 a0 = *(const float4*)(A_log + e*NN + n0);
      Aen[0]=-__expf(a0.x)*LOG2E; Aen[1]=-__expf(a0.y)*LOG2E;
      Aen[2]=-__expf(a0.z)*LOG2E; Aen[3]=-__expf(a0.w)*LOG2E;
      const float4 h0 = *(const float4*)(cP + (((size_t)c*BB + b)*ED + e)*NN + n0);
      h[0]=h0.x; h[1]=h0.y; h[2]=h0.z; h[3]=h0.w;
    }
    const float Dpe = Dpv[e];
    float pd[8], pu[8], pg[8];
    #pragma unroll
    for (int i = 0; i < 8; i++) {
      pd[i] = delta[(size_t)(t0+i)*ED + e];
      pu[i] = uc[(size_t)(t0+i)*ED + e];
      pg[i] = gate[(size_t)(t0+i)*ED + e];
    }
    for (int g4 = 0; g4 < 4; g4++) {
      float cd[8], cu[8], cg[8];
      #pragma unroll
      for (int i = 0; i < 8; i++) { cd[i]=pd[i]; cu[i]=pu[i]; cg[i]=pg[i]; }
      if (g4 < 3) {
        const int tn = t0 + (g4+1)*8;
        #pragma unroll
        for (int i = 0; i < 8; i++) {
          pd[i] = delta[(size_t)(tn+i)*ED + e];
          pu[i] = uc[(size_t)(tn+i)*ED + e];
          pg[i] = gate[(size_t)(tn+i)*ED + e];
        }
      }
      #pragma unroll
      for (int i = 0; i < 8; i++) {
        const int t = g4*8 + i;
        const float dv = cd[i];
        const float uv = cu[i];
        const float du = dv * uv;
        const float4 B0 = *(const float4*)&sbc[t][n0];
        const float4 C0 = *(const float4*)&sbc[t][16 + n0];
        const float Bv[4] = {B0.x,B0.y,B0.z,B0.w};
        const float Cv[4] = {C0.x,C0.y,C0.z,C0.w};
        float part = 0.f;
        #pragma unroll
        for (int j = 0; j < 4; j++) {
          h[j] = exp2_fast(dv * Aen[j])*h[j] + Bv[j]*du;
          part += h[j]*Cv[j];
        }
        part += __shfl_xor(part, 1);
        part += __shfl_xor(part, 2);
        if (q == 0)
          Au[t][e] = f2bf((part + uv*Dpe) * cg[i]);
      }
    }
  }
  __syncthreads();

  {
    const int mi = (wave & 1) * 16;
    const int wn = (wave >> 1) * 16;
    floatx4 acc = {};
    #pragma unroll
    for (int ks = 0; ks < 8; ks++) {
      const int ko = ks*32 + quad*8;
      short8 a  = *(const short8*)&Au[mi + l16][ko];
      short8 bv = *(const short8*)&BigW[(size_t)(wn + l16)*264 + ko];
      acc = __builtin_amdgcn_mfma_f32_16x16x32_bf16(a, bv, acc, 0, 0, 0);
    }
    const int n = wn + l16;
    #pragma unroll
    for (int r = 0; r < 4; r++) {
      const int m = mi + quad*4 + r;
      xs[m][n] = acc[r] + x[(size_t)(t0 + m)*DD + n];
    }
  }
  __syncthreads();

  if (tid < 512) {
    const int lr = tid >> 4, le = (tid & 15) * 8;
    float vv[8];
    float s = 0.f, sq = 0.f;
    #pragma unroll
    for (int i = 0; i < 8; i++) {
      vv[i] = xs[lr][le + i];
      s += vv[i]; sq += vv[i]*vv[i];
    }
    s += __shfl_xor(s, 1);  s += __shfl_xor(s, 2);
    s += __shfl_xor(s, 4);  s += __shfl_xor(s, 8);
    sq += __shfl_xor(sq, 1); sq += __shfl_xor(sq, 2);
    sq += __shfl_xor(sq, 4); sq += __shfl_xor(sq, 8);
    const float mean = s * (1.f/128.f);
    const float rs = rsqrtf(sq*(1.f/128.f) - mean*mean + 1e-5f);
    ushort8v p;
    #pragma unroll
    for (int i = 0; i < 8; i++)
      p[i] = f2bf((vv[i] - mean)*rs*g1[le + i] + b1[le + i]);
    *(ushort8v*)&Au[lr][le] = p;
  }
  {
    const int r = tid >> 2, k0 = (tid & 3) * 32;
    const float* wp = fc1_w + (size_t)r*DD + k0;
    #pragma unroll
    for (int g = 0; g < 4; g++) {
      const float4 v0 = *(const float4*)(wp + g*8);
      const float4 v1 = *(const float4*)(wp + g*8 + 4);
      *(ushort8v*)&BigW[(size_t)r*136 + k0 + g*8] = pack8(v0, v1);
    }
  }
  __syncthreads();

  {
    const int mi = (wave & 1) * 16;
    const int wn = (wave >> 1) * 32;
    floatx4 acc[2] = {};
    #pragma unroll
    for (int ks = 0; ks < 4; ks++) {
      const int ko = ks*32 + quad*8;
      short8 a  = *(const short8*)&Au[mi + l16][ko];
      short8 b0 = *(const short8*)&BigW[(size_t)(wn +      l16)*136 + ko];
      short8 b1 = *(const short8*)&BigW[(size_t)(wn + 16 + l16)*136 + ko];
      acc[0] = __builtin_amdgcn_mfma_f32_16x16x32_bf16(a, b0, acc[0], 0, 0, 0);
      acc[1] = __builtin_amdgcn_mfma_f32_16x16x32_bf16(a, b1, acc[1], 0, 0, 0);
    }
    __syncthreads();
    #pragma unroll
    for (int f = 0; f < 2; f++) {
      const int n = wn + f*16 + l16;
      const float bn = fc1_b[n];
      #pragma unroll
      for (int r = 0; r < 4; r++) {
        const int m = mi + quad*4 + r;
        float v = acc[f][r] + bn;
        v = 0.5f*v*(1.f + erff(v*0.70710678118f));
        Au[m][n] = f2bf(v);
      }
    }
  }
  {
    const int r = tid >> 3, k0 = (tid & 7) * 32;
    const float* wp = fc2_w + (size_t)r*HH + k0;
    #pragma unroll
    for (int g = 0; g < 4; g++) {
      const float4 v0 = *(const float4*)(wp + g*8);
      const float4 v1 = *(const float4*)(wp + g*8 + 4);
      *(ushort8v*)&BigW[(size_t)r*264 + k0 + g*8] = pack8(v0, v1);
    }
  }
  __syncthreads();

  {
    const int mi = (wave & 1) * 16;
    const int wn = (wave >> 1) * 16;
    floatx4 acc = {};
    #pragma unroll
    for (int ks = 0; ks < 8; ks++) {
      const int ko = ks*32 + quad*8;
      short8 a  = *(const short8*)&Au[mi + l16][ko];
      short8 bv = *(const short8*)&BigW[(size_t)(wn + l16)*264 + ko];
      acc = __builtin_amdgcn_mfma_f32_16x16x32_bf16(a, bv, acc, 0, 0, 0);
    }
    const int n = wn + l16;
    const float bn = fc2_b[n];
    #pragma unroll
    for (int r = 0; r < 4; r++) {
      const int m = mi + quad*4 + r;
      out[(size_t)(t0 + m)*DD + n] = acc[r] + bn + xs[m][n];
    }
  }
}

// ---------------------------------------------------------------------------
extern "C" void kernel_launch(void* const* d_in, const int* in_sizes, int n_in,
                              void* d_out, int out_size, void* d_ws, size_t ws_size,
                              hipStream_t stream) {
  const float* x      = (const float*)d_in[0];
  const float* n1g    = (const float*)d_in[1];
  const float* n1b    = (const float*)d_in[2];
  const float* ing    = (const float*)d_in[3];
  const float* inb    = (const float*)d_in[4];
  const float* in_w   = (const float*)d_in[5];
  const float* conv_w = (const float*)d_in[6];
  const float* conv_b = (const float*)d_in[7];
  const float* xproj_w= (const float*)d_in[8];
  const float* dt_w   = (const float*)d_in[9];
  const float* dt_b   = (const float*)d_in[10];
  const float* A_log  = (const float*)d_in[11];
  const float* Dpv    = (const float*)d_in[12];
  const float* out_w  = (const float*)d_in[13];
  const float* fc1_w  = (const float*)d_in[14];
  const float* fc1_b  = (const float*)d_in[15];
  const float* fc2_w  = (const float*)d_in[16];
  const float* fc2_b  = (const float*)d_in[17];
  float* out = (float*)d_out;

  // Workspace (~35 MB)
  float* ws    = (float*)d_ws;
  float* uc    = ws;                          // [NT,256]
  float* dbc   = uc    + (size_t)NT*ED;       // [NT,40]
  float* delta = dbc   + (size_t)NT*40;       // [NT,256]
  float* gate  = delta + (size_t)NT*ED;       // [NT,256]  silu(z)
  float* cA    = gate  + (size_t)NT*ED;       // [NC,B,ED,N]
  float* cH    = cA    + (size_t)NC*BB*ED*NN;

  // 1) fused LN+in_proj GEMM+conv+xproj+delta+summaries (no duplication)
  scan1h_k<<<dim3(NC, BB), 512, 0, stream>>>(x, n1g, n1b, ing, inb, in_w,
                                             conv_w, conv_b, xproj_w, dt_w, dt_b,
                                             A_log, uc, dbc, delta, gate, cA, cH);
  // 2) inter-chunk prefix (4-way segmented)
  scan2p_k<<<(4*BB*ED*NN)/256, 256, 0, stream>>>(cA, cH);
  // 3) scan replay + gate + out_proj + LN + MLP + residuals -> out
  tail7_k<<<dim3(NC, BB), 1024, 0, stream>>>(gate, delta, uc, dbc, cA, A_log, Dpv,
                                             x, n1g, n1b, out_w, fc1_w, fc1_b,
                                             fc2_w, fc2_b, out);
}